// Round 13
// baseline (94.162 us; speedup 1.0000x reference)
//
#include <hip/hip_runtime.h>
#include <hip/hip_bf16.h>
#include <math.h>

#define N_NODES 50000
#define N_EDGES 800000
#define IN_F 256
#define OUT_F 64

#define BKT 256            // nodes per bucket
#define NB 196             // ceil(50000/256)
#define CAP 6144           // fixed per-bucket capacity (mean 4096, sigma 64)
#define PARTA_BLOCKS 400   // 800000/400 = 2000 edges/block
#define EPB (N_EDGES / PARTA_BLOCKS)   // 2000
#define GEMM_BLOCKS 782    // ceil(50000/64)

typedef __attribute__((ext_vector_type(8))) short bf16x8;
typedef __attribute__((ext_vector_type(4))) float f32x4;

__device__ __forceinline__ ushort f2bf(float x) {
    __hip_bfloat16 b = __float2bfloat16(x);   // RNE
    return *reinterpret_cast<ushort*>(&b);
}
__device__ __forceinline__ float bf_lo(uint v) { return __uint_as_float(v << 16); }
__device__ __forceinline__ float bf_hi(uint v) { return __uint_as_float(v & 0xffff0000u); }

// ---------------------------------------------------------------------------
// 0) prep: block 0 zeros bcntD+bcntS (392 ints); blocks 1..8 pack W into
//    bf16 MFMA B-frag layout.
// ---------------------------------------------------------------------------
__global__ __launch_bounds__(256) void prep_kernel(int* __restrict__ bcnt,
                                                   const float* __restrict__ W,
                                                   ushort* __restrict__ Wpk) {
    const int tid = threadIdx.x;
    if (blockIdx.x == 0) {
        for (int i = tid; i < 2 * NB; i += 256) bcnt[i] = 0;
    } else {
        const int gid = (blockIdx.x - 1) * 256 + tid;   // 0..2047
        const int lane = gid & 63;
        const int ct = (gid >> 6) & 3;
        const int step = gid >> 8;
        const int kg = lane >> 4;
        const int n = lane & 15;
        const float* base = W + (size_t)(step * 32 + kg * 8) * OUT_F + ct * 16 + n;
        union { ushort u[8]; uint4 v; } pk;
        #pragma unroll
        for (int j = 0; j < 8; ++j) pk.u[j] = f2bf(base[(size_t)j * OUT_F]);
        ((uint4*)Wpk)[gid] = pk.v;
    }
}

// ---------------------------------------------------------------------------
// 1) fused: partA (latency/atomic-bound) overlapped with gemm (BW-bound)
//    in one launch. No data dependency: gemm writes RAW h (no norm_src;
//    norm applied in gather). Block roles interleaved so both workloads
//    co-run on every CU (MFMA and VALU/LDS pipes are separate).
//      bi in [0,800) odd  -> partA id (bi>>1)      (400 blocks)
//      bi in [0,800) even -> gemm  id (bi>>1)      (400 blocks)
//      bi in [800,1182)   -> gemm  id (bi-400)     (382 blocks)
// ---------------------------------------------------------------------------
__global__ __launch_bounds__(256) void fused_kernel(const int* __restrict__ src,
                                                    const int* __restrict__ dst,
                                                    int* __restrict__ bcntD,
                                                    int* __restrict__ bcntS,
                                                    uint* __restrict__ pairsD,
                                                    ushort* __restrict__ srcloc,
                                                    const float* __restrict__ feat,
                                                    const ushort* __restrict__ Wpk,
                                                    ushort* __restrict__ h) {
    const int bi = blockIdx.x;
    const int tid = threadIdx.x;

    if (bi < 2 * PARTA_BLOCKS && (bi & 1)) {
        // ----------------- partA role -----------------
        __shared__ int lcntD[NB], lbaseD[NB], lcntS[NB], lbaseS[NB];
        const int id = bi >> 1;
        const int n4 = EPB / 4;   // 500

        for (int i = tid; i < NB; i += 256) { lcntD[i] = 0; lcntS[i] = 0; }
        __syncthreads();

        const int4* t4 = (const int4*)(dst + (size_t)id * EPB);
        const int4* s4 = (const int4*)(src + (size_t)id * EPB);

        for (int i = tid; i < n4; i += 256) {
            const int4 d = t4[i];
            const int4 s = s4[i];
            atomicAdd(&lcntD[d.x >> 8], 1); atomicAdd(&lcntS[s.x >> 8], 1);
            atomicAdd(&lcntD[d.y >> 8], 1); atomicAdd(&lcntS[s.y >> 8], 1);
            atomicAdd(&lcntD[d.z >> 8], 1); atomicAdd(&lcntS[s.z >> 8], 1);
            atomicAdd(&lcntD[d.w >> 8], 1); atomicAdd(&lcntS[s.w >> 8], 1);
        }
        __syncthreads();

        for (int i = tid; i < NB; i += 256) {
            int c = lcntD[i];
            lbaseD[i] = c ? atomicAdd(&bcntD[i], c) : 0;
            lcntD[i] = 0;
            c = lcntS[i];
            lbaseS[i] = c ? atomicAdd(&bcntS[i], c) : 0;
            lcntS[i] = 0;
        }
        __syncthreads();

        for (int i = tid; i < n4; i += 256) {
            const int4 d = t4[i];
            const int4 s = s4[i];
            int bx, off;
            #define PLACE(dd, ss)                                                  \
                bx = (dd) >> 8; off = atomicAdd(&lcntD[bx], 1);                    \
                pairsD[(size_t)bx * CAP + lbaseD[bx] + off] =                      \
                    ((uint)((dd) & 255) << 16) | (uint)(ss);                       \
                bx = (ss) >> 8; off = atomicAdd(&lcntS[bx], 1);                    \
                srcloc[(size_t)bx * CAP + lbaseS[bx] + off] = (ushort)((ss) & 255);
            PLACE(d.x, s.x)
            PLACE(d.y, s.y)
            PLACE(d.z, s.z)
            PLACE(d.w, s.w)
            #undef PLACE
        }
    } else {
        // ----------------- gemm role: h_raw = bf16(feat @ W) -----------------
        const int id = (bi < 2 * PARTA_BLOCKS) ? (bi >> 1) : (bi - PARTA_BLOCKS);
        const int lane = tid & 63;
        const int wave = tid >> 6;
        const int m = lane & 15;
        const int g = lane >> 4;
        const int rowBase = id * 64 + wave * 16;

        f32x4 acc[4];
        #pragma unroll
        for (int ct = 0; ct < 4; ++ct) acc[ct] = (f32x4){0.f, 0.f, 0.f, 0.f};

        int arow = rowBase + m;
        if (arow >= N_NODES) arow = N_NODES - 1;   // clamp; stores guarded below
        const float* ap = feat + (size_t)arow * IN_F;
        const bf16x8* wp = (const bf16x8*)Wpk;

        #pragma unroll
        for (int step = 0; step < 8; ++step) {
            const int k0 = step * 32 + g * 8;
            const float4 a0 = *(const float4*)(ap + k0);
            const float4 a1 = *(const float4*)(ap + k0 + 4);
            bf16x8 aa;
            aa[0] = (short)f2bf(a0.x); aa[1] = (short)f2bf(a0.y);
            aa[2] = (short)f2bf(a0.z); aa[3] = (short)f2bf(a0.w);
            aa[4] = (short)f2bf(a1.x); aa[5] = (short)f2bf(a1.y);
            aa[6] = (short)f2bf(a1.z); aa[7] = (short)f2bf(a1.w);
            #pragma unroll
            for (int ct = 0; ct < 4; ++ct)
                acc[ct] = __builtin_amdgcn_mfma_f32_16x16x32_bf16(
                    aa, wp[(step * 4 + ct) * 64 + lane], acc[ct], 0, 0, 0);
        }

        // C-frag: col = ct*16 + m, row = rowBase + g*4 + j   [m89 verified]
        #pragma unroll
        for (int j = 0; j < 4; ++j) {
            const int row = rowBase + g * 4 + j;
            if (row < N_NODES) {
                #pragma unroll
                for (int ct = 0; ct < 4; ++ct)
                    h[(size_t)row * OUT_F + ct * 16 + m] = f2bf(acc[ct][j]);
            }
        }
    }
}

// ---------------------------------------------------------------------------
// 2) bucket: fused degB + partB. One block per 256-node bucket.
//    Phase 1: count srcloc locals -> normS = rsqrt(max(outdeg,1)).
//    Phase 2: count pairsD locals -> block scan -> ptr/indeg -> place
//    sorted_src within the bucket's CAP region.
// ---------------------------------------------------------------------------
__global__ __launch_bounds__(256) void bucket_kernel(const ushort* __restrict__ srcloc,
                                                     const int* __restrict__ bcntS,
                                                     float* __restrict__ normS,
                                                     const uint* __restrict__ pairsD,
                                                     const int* __restrict__ bcntD,
                                                     int* __restrict__ ptr,
                                                     int* __restrict__ indeg,
                                                     ushort* __restrict__ sorted_src) {
    __shared__ int cnt[BKT];
    __shared__ int loff[BKT];
    __shared__ int wtot[4];
    const int bb = blockIdx.x;
    const int tid = threadIdx.x;
    const int lane = tid & 63;
    const int wave = tid >> 6;
    const int node = bb * BKT + tid;

    // --- phase 1: out-degree -> normS ---
    cnt[tid] = 0;
    __syncthreads();
    const int nS = bcntS[bb];
    const ushort* sp = srcloc + (size_t)bb * CAP;
    for (int i = tid; i < nS; i += 256) atomicAdd(&cnt[sp[i]], 1);
    __syncthreads();
    if (node < N_NODES) normS[node] = rsqrtf(fmaxf((float)cnt[tid], 1.0f));
    __syncthreads();

    // --- phase 2: dst sort ---
    cnt[tid] = 0;
    __syncthreads();
    const int nD = bcntD[bb];
    const uint* pb = pairsD + (size_t)bb * CAP;
    for (int i = tid; i < nD; i += 256) atomicAdd(&cnt[pb[i] >> 16], 1);
    __syncthreads();

    const int v = cnt[tid];
    int incl = v;
    #pragma unroll
    for (int d = 1; d < 64; d <<= 1) {
        int u = __shfl_up(incl, d, 64);
        if (lane >= d) incl += u;
    }
    if (lane == 63) wtot[wave] = incl;
    __syncthreads();
    int woff = 0;
    #pragma unroll
    for (int w = 0; w < 4; ++w)
        if (w < wave) woff += wtot[w];
    const int ex = woff + incl - v;
    loff[tid] = ex;
    cnt[tid] = 0;                        // reuse as per-local cursor
    if (node < N_NODES) { ptr[node] = bb * CAP + ex; indeg[node] = v; }
    __syncthreads();

    for (int i = tid; i < nD; i += 256) {
        const uint p = pb[i];
        const int local = (int)(p >> 16);
        const int pos = atomicAdd(&cnt[local], 1);
        sorted_src[(size_t)bb * CAP + loff[local] + pos] = (ushort)(p & 0xFFFFu);
    }
}

// ---------------------------------------------------------------------------
// 3) Gather + epilogue: one wave per dst node, QUARTER-wave per edge
//    (16 lanes x 8 B = full 128 B h-row), 4 edges/iter. Each gathered row
//    scaled by normS[src] (moved out of gemm to break the dependency).
// ---------------------------------------------------------------------------
__global__ __launch_bounds__(256) void gather_kernel(const int* __restrict__ ptr,
                                                     const int* __restrict__ indeg,
                                                     const ushort* __restrict__ sorted_src,
                                                     const float* __restrict__ normS,
                                                     const ushort* __restrict__ h,
                                                     const float* __restrict__ b,
                                                     float* __restrict__ out) {
    const int lane = threadIdx.x & 63;
    const int q = lane & 15;           // col group: cols q*4 .. q*4+3
    const int g = lane >> 4;           // edge slot 0..3
    int nid = (int)((blockIdx.x * (size_t)blockDim.x + threadIdx.x) >> 6);
    if (nid >= N_NODES) return;
    nid = __builtin_amdgcn_readfirstlane(nid);

    const int beg = ptr[nid];
    const int deg = indeg[nid];

    float a0 = 0.f, a1 = 0.f, a2 = 0.f, a3 = 0.f;
    const int nfull = deg >> 2;
    int e = beg + g;
    #pragma unroll 4
    for (int i = 0; i < nfull; ++i) {
        const int s = (int)sorted_src[e];
        e += 4;
        const float ns = normS[s];
        const uint2 v = *(const uint2*)(h + (size_t)s * OUT_F + q * 4);
        a0 = fmaf(ns, bf_lo(v.x), a0); a1 = fmaf(ns, bf_hi(v.x), a1);
        a2 = fmaf(ns, bf_lo(v.y), a2); a3 = fmaf(ns, bf_hi(v.y), a3);
    }
    const int rem = deg & 3;
    if (g < rem) {
        const int s = (int)sorted_src[beg + (deg & ~3) + g];
        const float ns = normS[s];
        const uint2 v = *(const uint2*)(h + (size_t)s * OUT_F + q * 4);
        a0 = fmaf(ns, bf_lo(v.x), a0); a1 = fmaf(ns, bf_hi(v.x), a1);
        a2 = fmaf(ns, bf_lo(v.y), a2); a3 = fmaf(ns, bf_hi(v.y), a3);
    }
    // combine the 4 edge-slot groups (flip g bits: xor 16, xor 32)
    a0 += __shfl_xor(a0, 16, 64); a1 += __shfl_xor(a1, 16, 64);
    a2 += __shfl_xor(a2, 16, 64); a3 += __shfl_xor(a3, 16, 64);
    a0 += __shfl_xor(a0, 32, 64); a1 += __shfl_xor(a1, 32, 64);
    a2 += __shfl_xor(a2, 32, 64); a3 += __shfl_xor(a3, 32, 64);

    if (g == 0) {
        const float norm = rsqrtf(fmaxf((float)deg, 1.0f));
        const float4 bb = *(const float4*)(b + q * 4);
        float4 o;
        o.x = 1.0f / (1.0f + expf(-(a0 * norm + bb.x)));
        o.y = 1.0f / (1.0f + expf(-(a1 * norm + bb.y)));
        o.z = 1.0f / (1.0f + expf(-(a2 * norm + bb.z)));
        o.w = 1.0f / (1.0f + expf(-(a3 * norm + bb.w)));
        *(float4*)(out + (size_t)nid * OUT_F + q * 4) = o;
    }
}

// ---------------------------------------------------------------------------
extern "C" void kernel_launch(void* const* d_in, const int* in_sizes, int n_in,
                              void* d_out, int out_size, void* d_ws, size_t ws_size,
                              hipStream_t stream) {
    const float* feat = (const float*)d_in[0];
    const int* src    = (const int*)d_in[1];
    const int* dst    = (const int*)d_in[2];
    const float* W    = (const float*)d_in[3];
    const float* b    = (const float*)d_in[4];
    float* out = (float*)d_out;

    char* ws = (char*)d_ws;
    size_t off = 0;
    ushort* h = (ushort*)(ws + off);        off += (size_t)N_NODES * OUT_F * 2;  // 6.4 MB
    float* normS = (float*)(ws + off);      off += (size_t)N_NODES * 4;          // 200 KB
    int* indeg = (int*)(ws + off);          off += (size_t)N_NODES * 4;          // 200 KB
    int* ptr = (int*)(ws + off);            off += (size_t)N_NODES * 4;          // 200 KB
    int* bcnt = (int*)(ws + off);           off += (size_t)2 * NB * 4;           // bcntD|bcntS
    ushort* Wpk = (ushort*)(ws + off);      off += (size_t)IN_F * OUT_F * 2;     // 32 KB
    uint* pairsD = (uint*)(ws + off);       off += (size_t)NB * CAP * 4;         // 4.8 MB
    ushort* srcloc = (ushort*)(ws + off);   off += (size_t)NB * CAP * 2;         // 2.4 MB
    ushort* sorted_src = (ushort*)(ws + off); off += (size_t)NB * CAP * 2;       // 2.4 MB
    int* bcntD = bcnt;
    int* bcntS = bcnt + NB;

    prep_kernel<<<9, 256, 0, stream>>>(bcnt, W, Wpk);

    fused_kernel<<<PARTA_BLOCKS + GEMM_BLOCKS, 256, 0, stream>>>(
        src, dst, bcntD, bcntS, pairsD, srcloc, feat, Wpk, h);

    bucket_kernel<<<NB, 256, 0, stream>>>(srcloc, bcntS, normS,
                                          pairsD, bcntD, ptr, indeg, sorted_src);

    gather_kernel<<<(N_NODES * 64 + 255) / 256, 256, 0, stream>>>(
        ptr, indeg, sorted_src, normS, h, b, out);
}

// Round 14
// 90.033 us; speedup vs baseline: 1.0459x; 1.0459x over previous
//
#include <hip/hip_runtime.h>
#include <hip/hip_bf16.h>
#include <math.h>

#define N_NODES 50000
#define N_EDGES 800000
#define IN_F 256
#define OUT_F 64

#define BKT 256            // nodes per bucket
#define NB 196             // ceil(50000/256)
#define CAP 6144           // fixed per-bucket capacity (mean 4096, sigma 64)
#define PARTA_BLOCKS 400   // 800000/400 = 2000 edges/block
#define EPB (N_EDGES / PARTA_BLOCKS)   // 2000
#define GEMM_BM 64

typedef __attribute__((ext_vector_type(8))) short bf16x8;
typedef __attribute__((ext_vector_type(4))) float f32x4;

__device__ __forceinline__ ushort f2bf(float x) {
    __hip_bfloat16 b = __float2bfloat16(x);   // RNE
    return *reinterpret_cast<ushort*>(&b);
}
__device__ __forceinline__ float bf_lo(uint v) { return __uint_as_float(v << 16); }
__device__ __forceinline__ float bf_hi(uint v) { return __uint_as_float(v & 0xffff0000u); }

// ---------------------------------------------------------------------------
// 0) prep: block 0 zeros bcntD+bcntS; blocks 1..8 pack W into bf16 MFMA
//    B-frag layout.
// ---------------------------------------------------------------------------
__global__ __launch_bounds__(256) void prep_kernel(int* __restrict__ bcnt,
                                                   const float* __restrict__ W,
                                                   ushort* __restrict__ Wpk) {
    const int tid = threadIdx.x;
    if (blockIdx.x == 0) {
        for (int i = tid; i < 2 * NB; i += 256) bcnt[i] = 0;
    } else {
        const int gid = (blockIdx.x - 1) * 256 + tid;   // 0..2047
        const int lane = gid & 63;
        const int ct = (gid >> 6) & 3;
        const int step = gid >> 8;
        const int kg = lane >> 4;
        const int n = lane & 15;
        const float* base = W + (size_t)(step * 32 + kg * 8) * OUT_F + ct * 16 + n;
        union { ushort u[8]; uint4 v; } pk;
        #pragma unroll
        for (int j = 0; j < 8; ++j) pk.u[j] = f2bf(base[(size_t)j * OUT_F]);
        ((uint4*)Wpk)[gid] = pk.v;
    }
}

// ---------------------------------------------------------------------------
// 1) partA: dual bucket-partition, one pass over the edge list.
//    dst-buckets: pairsD[b*CAP + i] = (dst&255)<<16 | src
//    src-buckets: srcloc[b*CAP + i] = src&255
// ---------------------------------------------------------------------------
__global__ __launch_bounds__(256) void partA_kernel(const int* __restrict__ src,
                                                    const int* __restrict__ dst,
                                                    int* __restrict__ bcntD,
                                                    int* __restrict__ bcntS,
                                                    uint* __restrict__ pairsD,
                                                    ushort* __restrict__ srcloc) {
    __shared__ int lcntD[NB], lbaseD[NB], lcntS[NB], lbaseS[NB];
    const int tid = threadIdx.x;
    const int n4 = EPB / 4;   // 500

    for (int i = tid; i < NB; i += 256) { lcntD[i] = 0; lcntS[i] = 0; }
    __syncthreads();

    const int4* t4 = (const int4*)(dst + (size_t)blockIdx.x * EPB);
    const int4* s4 = (const int4*)(src + (size_t)blockIdx.x * EPB);

    for (int i = tid; i < n4; i += 256) {
        const int4 d = t4[i];
        const int4 s = s4[i];
        atomicAdd(&lcntD[d.x >> 8], 1); atomicAdd(&lcntS[s.x >> 8], 1);
        atomicAdd(&lcntD[d.y >> 8], 1); atomicAdd(&lcntS[s.y >> 8], 1);
        atomicAdd(&lcntD[d.z >> 8], 1); atomicAdd(&lcntS[s.z >> 8], 1);
        atomicAdd(&lcntD[d.w >> 8], 1); atomicAdd(&lcntS[s.w >> 8], 1);
    }
    __syncthreads();

    for (int i = tid; i < NB; i += 256) {
        int c = lcntD[i];
        lbaseD[i] = c ? atomicAdd(&bcntD[i], c) : 0;
        lcntD[i] = 0;
        c = lcntS[i];
        lbaseS[i] = c ? atomicAdd(&bcntS[i], c) : 0;
        lcntS[i] = 0;
    }
    __syncthreads();

    for (int i = tid; i < n4; i += 256) {
        const int4 d = t4[i];
        const int4 s = s4[i];
        int bx, off;
        #define PLACE(dd, ss)                                                  \
            bx = (dd) >> 8; off = atomicAdd(&lcntD[bx], 1);                    \
            pairsD[(size_t)bx * CAP + lbaseD[bx] + off] =                      \
                ((uint)((dd) & 255) << 16) | (uint)(ss);                       \
            bx = (ss) >> 8; off = atomicAdd(&lcntS[bx], 1);                    \
            srcloc[(size_t)bx * CAP + lbaseS[bx] + off] = (ushort)((ss) & 255);
        PLACE(d.x, s.x)
        PLACE(d.y, s.y)
        PLACE(d.z, s.z)
        PLACE(d.w, s.w)
        #undef PLACE
    }
}

// ---------------------------------------------------------------------------
// 2) bucket: fused degB + partB. Phase 1: srcloc counts -> normS.
//    Phase 2: pairsD counts -> scan -> ptr/indeg -> place sorted_src.
// ---------------------------------------------------------------------------
__global__ __launch_bounds__(256) void bucket_kernel(const ushort* __restrict__ srcloc,
                                                     const int* __restrict__ bcntS,
                                                     float* __restrict__ normS,
                                                     const uint* __restrict__ pairsD,
                                                     const int* __restrict__ bcntD,
                                                     int* __restrict__ ptr,
                                                     int* __restrict__ indeg,
                                                     ushort* __restrict__ sorted_src) {
    __shared__ int cnt[BKT];
    __shared__ int loff[BKT];
    __shared__ int wtot[4];
    const int bb = blockIdx.x;
    const int tid = threadIdx.x;
    const int lane = tid & 63;
    const int wave = tid >> 6;
    const int node = bb * BKT + tid;

    // --- phase 1: out-degree -> normS ---
    cnt[tid] = 0;
    __syncthreads();
    const int nS = bcntS[bb];
    const ushort* sp = srcloc + (size_t)bb * CAP;
    for (int i = tid; i < nS; i += 256) atomicAdd(&cnt[sp[i]], 1);
    __syncthreads();
    if (node < N_NODES) normS[node] = rsqrtf(fmaxf((float)cnt[tid], 1.0f));
    __syncthreads();

    // --- phase 2: dst sort ---
    cnt[tid] = 0;
    __syncthreads();
    const int nD = bcntD[bb];
    const uint* pb = pairsD + (size_t)bb * CAP;
    for (int i = tid; i < nD; i += 256) atomicAdd(&cnt[pb[i] >> 16], 1);
    __syncthreads();

    const int v = cnt[tid];
    int incl = v;
    #pragma unroll
    for (int d = 1; d < 64; d <<= 1) {
        int u = __shfl_up(incl, d, 64);
        if (lane >= d) incl += u;
    }
    if (lane == 63) wtot[wave] = incl;
    __syncthreads();
    int woff = 0;
    #pragma unroll
    for (int w = 0; w < 4; ++w)
        if (w < wave) woff += wtot[w];
    const int ex = woff + incl - v;
    loff[tid] = ex;
    cnt[tid] = 0;                        // reuse as per-local cursor
    if (node < N_NODES) { ptr[node] = bb * CAP + ex; indeg[node] = v; }
    __syncthreads();

    for (int i = tid; i < nD; i += 256) {
        const uint p = pb[i];
        const int local = (int)(p >> 16);
        const int pos = atomicAdd(&cnt[local], 1);
        sorted_src[(size_t)bb * CAP + loff[local] + pos] = (ushort)(p & 0xFFFFu);
    }
}

// ---------------------------------------------------------------------------
// 3) gemm: h_raw = bf16(feat @ W) via MFMA, LDS-staged A.
//    Block stages its 64x256 f32 tile (64 KB) via global_load_lds width-16
//    (contiguous streams). XOR-swizzle (guide rule #21, both sides):
//    LDS dest linear, SOURCE chunk = (lane*16) ^ ((row&7)<<4), ds_read
//    applies the same XOR -> even 8-lane spread over all 8 bank groups.
// ---------------------------------------------------------------------------
__global__ __launch_bounds__(256) void gemm_kernel(const float* __restrict__ feat,
                                                   const ushort* __restrict__ Wpk,
                                                   ushort* __restrict__ h) {
    __shared__ float ftile[GEMM_BM * IN_F];   // 64 KB
    const int tid = threadIdx.x;
    const int lane = tid & 63;
    const int wave = tid >> 6;
    const int m = lane & 15;
    const int g = lane >> 4;
    const int rowBase = blockIdx.x * GEMM_BM;
    const char* fb = (const char*)feat;

    // async stage: 16 x (wave-uniform LDS base, per-lane pre-swizzled source)
    #pragma unroll
    for (int it = 0; it < 16; ++it) {
        const int R = it * 4 + wave;                        // tile row (uniform)
        const int off = (lane * 16) ^ ((R & 7) << 4);       // swizzled src chunk
        int grow = rowBase + R;
        if (grow >= N_NODES) grow = N_NODES - 1;            // clamp (dup row)
        __builtin_amdgcn_global_load_lds(
            (const __attribute__((address_space(1))) void*)(fb + ((size_t)grow << 10) + off),
            (__attribute__((address_space(3))) void*)((char*)ftile + it * 4096 + wave * 1024),
            16, 0, 0);
    }
    __syncthreads();

    f32x4 acc[4];
    #pragma unroll
    for (int ct = 0; ct < 4; ++ct) acc[ct] = (f32x4){0.f, 0.f, 0.f, 0.f};

    const int Rr = wave * 16 + m;              // A-frag row within tile
    const int swz = (Rr & 7) << 4;
    const char* rowb = (const char*)ftile + (Rr << 10);
    const bf16x8* wp = (const bf16x8*)Wpk;

    #pragma unroll
    for (int step = 0; step < 8; ++step) {
        const int kb = step * 128 + g * 32;
        const float4 a0 = *(const float4*)(rowb + (kb ^ swz));
        const float4 a1 = *(const float4*)(rowb + ((kb + 16) ^ swz));
        bf16x8 aa;
        aa[0] = (short)f2bf(a0.x); aa[1] = (short)f2bf(a0.y);
        aa[2] = (short)f2bf(a0.z); aa[3] = (short)f2bf(a0.w);
        aa[4] = (short)f2bf(a1.x); aa[5] = (short)f2bf(a1.y);
        aa[6] = (short)f2bf(a1.z); aa[7] = (short)f2bf(a1.w);
        #pragma unroll
        for (int ct = 0; ct < 4; ++ct)
            acc[ct] = __builtin_amdgcn_mfma_f32_16x16x32_bf16(
                aa, wp[(step * 4 + ct) * 64 + lane], acc[ct], 0, 0, 0);
    }

    // C-frag: col = ct*16 + m, row = rowBase + wave*16 + g*4 + j  [m89]
    #pragma unroll
    for (int j = 0; j < 4; ++j) {
        const int row = rowBase + wave * 16 + g * 4 + j;
        if (row < N_NODES) {
            #pragma unroll
            for (int ct = 0; ct < 4; ++ct)
                h[(size_t)row * OUT_F + ct * 16 + m] = f2bf(acc[ct][j]);
        }
    }
}

// ---------------------------------------------------------------------------
// 4) Gather + epilogue: one wave per dst node, quarter-wave per edge,
//    gathered rows scaled by normS[src].
// ---------------------------------------------------------------------------
__global__ __launch_bounds__(256) void gather_kernel(const int* __restrict__ ptr,
                                                     const int* __restrict__ indeg,
                                                     const ushort* __restrict__ sorted_src,
                                                     const float* __restrict__ normS,
                                                     const ushort* __restrict__ h,
                                                     const float* __restrict__ b,
                                                     float* __restrict__ out) {
    const int lane = threadIdx.x & 63;
    const int q = lane & 15;           // col group: cols q*4 .. q*4+3
    const int g = lane >> 4;           // edge slot 0..3
    int nid = (int)((blockIdx.x * (size_t)blockDim.x + threadIdx.x) >> 6);
    if (nid >= N_NODES) return;
    nid = __builtin_amdgcn_readfirstlane(nid);

    const int beg = ptr[nid];
    const int deg = indeg[nid];

    float a0 = 0.f, a1 = 0.f, a2 = 0.f, a3 = 0.f;
    const int nfull = deg >> 2;
    int e = beg + g;
    #pragma unroll 4
    for (int i = 0; i < nfull; ++i) {
        const int s = (int)sorted_src[e];
        e += 4;
        const float ns = normS[s];
        const uint2 v = *(const uint2*)(h + (size_t)s * OUT_F + q * 4);
        a0 = fmaf(ns, bf_lo(v.x), a0); a1 = fmaf(ns, bf_hi(v.x), a1);
        a2 = fmaf(ns, bf_lo(v.y), a2); a3 = fmaf(ns, bf_hi(v.y), a3);
    }
    const int rem = deg & 3;
    if (g < rem) {
        const int s = (int)sorted_src[beg + (deg & ~3) + g];
        const float ns = normS[s];
        const uint2 v = *(const uint2*)(h + (size_t)s * OUT_F + q * 4);
        a0 = fmaf(ns, bf_lo(v.x), a0); a1 = fmaf(ns, bf_hi(v.x), a1);
        a2 = fmaf(ns, bf_lo(v.y), a2); a3 = fmaf(ns, bf_hi(v.y), a3);
    }
    a0 += __shfl_xor(a0, 16, 64); a1 += __shfl_xor(a1, 16, 64);
    a2 += __shfl_xor(a2, 16, 64); a3 += __shfl_xor(a3, 16, 64);
    a0 += __shfl_xor(a0, 32, 64); a1 += __shfl_xor(a1, 32, 64);
    a2 += __shfl_xor(a2, 32, 64); a3 += __shfl_xor(a3, 32, 64);

    if (g == 0) {
        const float norm = rsqrtf(fmaxf((float)deg, 1.0f));
        const float4 bb = *(const float4*)(b + q * 4);
        float4 o;
        o.x = 1.0f / (1.0f + expf(-(a0 * norm + bb.x)));
        o.y = 1.0f / (1.0f + expf(-(a1 * norm + bb.y)));
        o.z = 1.0f / (1.0f + expf(-(a2 * norm + bb.z)));
        o.w = 1.0f / (1.0f + expf(-(a3 * norm + bb.w)));
        *(float4*)(out + (size_t)nid * OUT_F + q * 4) = o;
    }
}

// ---------------------------------------------------------------------------
extern "C" void kernel_launch(void* const* d_in, const int* in_sizes, int n_in,
                              void* d_out, int out_size, void* d_ws, size_t ws_size,
                              hipStream_t stream) {
    const float* feat = (const float*)d_in[0];
    const int* src    = (const int*)d_in[1];
    const int* dst    = (const int*)d_in[2];
    const float* W    = (const float*)d_in[3];
    const float* b    = (const float*)d_in[4];
    float* out = (float*)d_out;

    char* ws = (char*)d_ws;
    size_t off = 0;
    ushort* h = (ushort*)(ws + off);        off += (size_t)N_NODES * OUT_F * 2;  // 6.4 MB
    float* normS = (float*)(ws + off);      off += (size_t)N_NODES * 4;          // 200 KB
    int* indeg = (int*)(ws + off);          off += (size_t)N_NODES * 4;          // 200 KB
    int* ptr = (int*)(ws + off);            off += (size_t)N_NODES * 4;          // 200 KB
    int* bcnt = (int*)(ws + off);           off += (size_t)2 * NB * 4;           // bcntD|bcntS
    ushort* Wpk = (ushort*)(ws + off);      off += (size_t)IN_F * OUT_F * 2;     // 32 KB
    uint* pairsD = (uint*)(ws + off);       off += (size_t)NB * CAP * 4;         // 4.8 MB
    ushort* srcloc = (ushort*)(ws + off);   off += (size_t)NB * CAP * 2;         // 2.4 MB
    ushort* sorted_src = (ushort*)(ws + off); off += (size_t)NB * CAP * 2;       // 2.4 MB
    int* bcntD = bcnt;
    int* bcntS = bcnt + NB;

    prep_kernel<<<9, 256, 0, stream>>>(bcnt, W, Wpk);

    partA_kernel<<<PARTA_BLOCKS, 256, 0, stream>>>(src, dst, bcntD, bcntS, pairsD, srcloc);

    bucket_kernel<<<NB, 256, 0, stream>>>(srcloc, bcntS, normS,
                                          pairsD, bcntD, ptr, indeg, sorted_src);

    gemm_kernel<<<(N_NODES + GEMM_BM - 1) / GEMM_BM, 256, 0, stream>>>(feat, Wpk, h);

    gather_kernel<<<(N_NODES * 64 + 255) / 256, 256, 0, stream>>>(
        ptr, indeg, sorted_src, normS, h, b, out);
}

// Round 15
// 84.367 us; speedup vs baseline: 1.1161x; 1.0672x over previous
//
#include <hip/hip_runtime.h>
#include <hip/hip_bf16.h>
#include <math.h>

#define N_NODES 50000
#define N_EDGES 800000
#define IN_F 256
#define OUT_F 64

#define BKT 256            // nodes per bucket
#define NB 196             // ceil(50000/256)
#define CAP 6144           // fixed per-bucket capacity (mean 4096, sigma 64)
#define PARTA_BLOCKS 400   // 800000/400 = 2000 edges/block
#define EPB (N_EDGES / PARTA_BLOCKS)   // 2000
#define GEMM_BM 64

typedef __attribute__((ext_vector_type(8))) short bf16x8;
typedef __attribute__((ext_vector_type(4))) float f32x4;

__device__ __forceinline__ ushort f2bf(float x) {
    __hip_bfloat16 b = __float2bfloat16(x);   // RNE
    return *reinterpret_cast<ushort*>(&b);
}
__device__ __forceinline__ float bf_lo(uint v) { return __uint_as_float(v << 16); }
__device__ __forceinline__ float bf_hi(uint v) { return __uint_as_float(v & 0xffff0000u); }

// ---------------------------------------------------------------------------
// 0) prep: block 0 zeros bcntD+bcntS; blocks 1..8 pack W into bf16 MFMA
//    B-frag layout.
// ---------------------------------------------------------------------------
__global__ __launch_bounds__(256) void prep_kernel(int* __restrict__ bcnt,
                                                   const float* __restrict__ W,
                                                   ushort* __restrict__ Wpk) {
    const int tid = threadIdx.x;
    if (blockIdx.x == 0) {
        for (int i = tid; i < 2 * NB; i += 256) bcnt[i] = 0;
    } else {
        const int gid = (blockIdx.x - 1) * 256 + tid;   // 0..2047
        const int lane = gid & 63;
        const int ct = (gid >> 6) & 3;
        const int step = gid >> 8;
        const int kg = lane >> 4;
        const int n = lane & 15;
        const float* base = W + (size_t)(step * 32 + kg * 8) * OUT_F + ct * 16 + n;
        union { ushort u[8]; uint4 v; } pk;
        #pragma unroll
        for (int j = 0; j < 8; ++j) pk.u[j] = f2bf(base[(size_t)j * OUT_F]);
        ((uint4*)Wpk)[gid] = pk.v;
    }
}

// ---------------------------------------------------------------------------
// 1) partA: dual bucket-partition, one pass over the edge list.
//    512 threads/block: halves per-thread atomic/scatter chain length and
//    doubles resident waves vs the 256-thread version.
// ---------------------------------------------------------------------------
__global__ __launch_bounds__(512) void partA_kernel(const int* __restrict__ src,
                                                    const int* __restrict__ dst,
                                                    int* __restrict__ bcntD,
                                                    int* __restrict__ bcntS,
                                                    uint* __restrict__ pairsD,
                                                    ushort* __restrict__ srcloc) {
    __shared__ int lcntD[NB], lbaseD[NB], lcntS[NB], lbaseS[NB];
    const int tid = threadIdx.x;
    const int n4 = EPB / 4;   // 500

    for (int i = tid; i < NB; i += 512) { lcntD[i] = 0; lcntS[i] = 0; }
    __syncthreads();

    const int4* t4 = (const int4*)(dst + (size_t)blockIdx.x * EPB);
    const int4* s4 = (const int4*)(src + (size_t)blockIdx.x * EPB);

    for (int i = tid; i < n4; i += 512) {
        const int4 d = t4[i];
        const int4 s = s4[i];
        atomicAdd(&lcntD[d.x >> 8], 1); atomicAdd(&lcntS[s.x >> 8], 1);
        atomicAdd(&lcntD[d.y >> 8], 1); atomicAdd(&lcntS[s.y >> 8], 1);
        atomicAdd(&lcntD[d.z >> 8], 1); atomicAdd(&lcntS[s.z >> 8], 1);
        atomicAdd(&lcntD[d.w >> 8], 1); atomicAdd(&lcntS[s.w >> 8], 1);
    }
    __syncthreads();

    for (int i = tid; i < NB; i += 512) {
        int c = lcntD[i];
        lbaseD[i] = c ? atomicAdd(&bcntD[i], c) : 0;
        lcntD[i] = 0;
        c = lcntS[i];
        lbaseS[i] = c ? atomicAdd(&bcntS[i], c) : 0;
        lcntS[i] = 0;
    }
    __syncthreads();

    for (int i = tid; i < n4; i += 512) {
        const int4 d = t4[i];
        const int4 s = s4[i];
        int bx, off;
        #define PLACE(dd, ss)                                                  \
            bx = (dd) >> 8; off = atomicAdd(&lcntD[bx], 1);                    \
            pairsD[(size_t)bx * CAP + lbaseD[bx] + off] =                      \
                ((uint)((dd) & 255) << 16) | (uint)(ss);                       \
            bx = (ss) >> 8; off = atomicAdd(&lcntS[bx], 1);                    \
            srcloc[(size_t)bx * CAP + lbaseS[bx] + off] = (ushort)((ss) & 255);
        PLACE(d.x, s.x)
        PLACE(d.y, s.y)
        PLACE(d.z, s.z)
        PLACE(d.w, s.w)
        #undef PLACE
    }
}

// ---------------------------------------------------------------------------
// 2) bucket: fused degB + partB, 512 threads. Count/place loops use all 512;
//    the 256-wide scan runs on waves 0-3 (wave-complete, sync-safe).
// ---------------------------------------------------------------------------
__global__ __launch_bounds__(512) void bucket_kernel(const ushort* __restrict__ srcloc,
                                                     const int* __restrict__ bcntS,
                                                     float* __restrict__ normS,
                                                     const uint* __restrict__ pairsD,
                                                     const int* __restrict__ bcntD,
                                                     int* __restrict__ ptr,
                                                     int* __restrict__ indeg,
                                                     ushort* __restrict__ sorted_src) {
    __shared__ int cnt[BKT];
    __shared__ int loff[BKT];
    __shared__ int wtot[4];
    const int bb = blockIdx.x;
    const int tid = threadIdx.x;
    const int node = bb * BKT + tid;   // valid meaning only for tid<256

    // --- phase 1: out-degree -> normS ---
    if (tid < BKT) cnt[tid] = 0;
    __syncthreads();
    const int nS = bcntS[bb];
    const ushort* sp = srcloc + (size_t)bb * CAP;
    for (int i = tid; i < nS; i += 512) atomicAdd(&cnt[sp[i]], 1);
    __syncthreads();
    if (tid < BKT && node < N_NODES)
        normS[node] = rsqrtf(fmaxf((float)cnt[tid], 1.0f));
    __syncthreads();

    // --- phase 2: dst sort ---
    if (tid < BKT) cnt[tid] = 0;
    __syncthreads();
    const int nD = bcntD[bb];
    const uint* pb = pairsD + (size_t)bb * CAP;
    for (int i = tid; i < nD; i += 512) atomicAdd(&cnt[pb[i] >> 16], 1);
    __syncthreads();

    // scan on waves 0-3
    if (tid < BKT) {
        const int lane = tid & 63;
        const int wave = tid >> 6;
        const int v = cnt[tid];
        int incl = v;
        #pragma unroll
        for (int d = 1; d < 64; d <<= 1) {
            int u = __shfl_up(incl, d, 64);
            if (lane >= d) incl += u;
        }
        if (lane == 63) wtot[wave] = incl;
        loff[tid] = incl - v;            // temp: intra-wave exclusive
    }
    __syncthreads();
    if (tid < BKT) {
        const int wave = tid >> 6;
        int woff = 0;
        #pragma unroll
        for (int w = 0; w < 4; ++w)
            if (w < wave) woff += wtot[w];
        const int ex = woff + loff[tid];
        loff[tid] = ex;
        const int v = cnt[tid];
        cnt[tid] = 0;                    // reuse as per-local cursor
        if (node < N_NODES) { ptr[node] = bb * CAP + ex; indeg[node] = v; }
    }
    __syncthreads();

    for (int i = tid; i < nD; i += 512) {
        const uint p = pb[i];
        const int local = (int)(p >> 16);
        const int pos = atomicAdd(&cnt[local], 1);
        sorted_src[(size_t)bb * CAP + loff[local] + pos] = (ushort)(p & 0xFFFFu);
    }
}

// ---------------------------------------------------------------------------
// 3) gemm: h_raw = bf16(feat @ W) via MFMA, LDS-staged A (round-14, kept).
// ---------------------------------------------------------------------------
__global__ __launch_bounds__(256) void gemm_kernel(const float* __restrict__ feat,
                                                   const ushort* __restrict__ Wpk,
                                                   ushort* __restrict__ h) {
    __shared__ float ftile[GEMM_BM * IN_F];   // 64 KB
    const int tid = threadIdx.x;
    const int lane = tid & 63;
    const int wave = tid >> 6;
    const int m = lane & 15;
    const int g = lane >> 4;
    const int rowBase = blockIdx.x * GEMM_BM;
    const char* fb = (const char*)feat;

    #pragma unroll
    for (int it = 0; it < 16; ++it) {
        const int R = it * 4 + wave;                        // tile row (uniform)
        const int off = (lane * 16) ^ ((R & 7) << 4);       // swizzled src chunk
        int grow = rowBase + R;
        if (grow >= N_NODES) grow = N_NODES - 1;            // clamp (dup row)
        __builtin_amdgcn_global_load_lds(
            (const __attribute__((address_space(1))) void*)(fb + ((size_t)grow << 10) + off),
            (__attribute__((address_space(3))) void*)((char*)ftile + it * 4096 + wave * 1024),
            16, 0, 0);
    }
    __syncthreads();

    f32x4 acc[4];
    #pragma unroll
    for (int ct = 0; ct < 4; ++ct) acc[ct] = (f32x4){0.f, 0.f, 0.f, 0.f};

    const int Rr = wave * 16 + m;              // A-frag row within tile
    const int swz = (Rr & 7) << 4;
    const char* rowb = (const char*)ftile + (Rr << 10);
    const bf16x8* wp = (const bf16x8*)Wpk;

    #pragma unroll
    for (int step = 0; step < 8; ++step) {
        const int kb = step * 128 + g * 32;
        const float4 a0 = *(const float4*)(rowb + (kb ^ swz));
        const float4 a1 = *(const float4*)(rowb + ((kb + 16) ^ swz));
        bf16x8 aa;
        aa[0] = (short)f2bf(a0.x); aa[1] = (short)f2bf(a0.y);
        aa[2] = (short)f2bf(a0.z); aa[3] = (short)f2bf(a0.w);
        aa[4] = (short)f2bf(a1.x); aa[5] = (short)f2bf(a1.y);
        aa[6] = (short)f2bf(a1.z); aa[7] = (short)f2bf(a1.w);
        #pragma unroll
        for (int ct = 0; ct < 4; ++ct)
            acc[ct] = __builtin_amdgcn_mfma_f32_16x16x32_bf16(
                aa, wp[(step * 4 + ct) * 64 + lane], acc[ct], 0, 0, 0);
    }

    #pragma unroll
    for (int j = 0; j < 4; ++j) {
        const int row = rowBase + wave * 16 + g * 4 + j;
        if (row < N_NODES) {
            #pragma unroll
            for (int ct = 0; ct < 4; ++ct)
                h[(size_t)row * OUT_F + ct * 16 + m] = f2bf(acc[ct][j]);
        }
    }
}

// ---------------------------------------------------------------------------
// 4) Gather + epilogue: one wave per dst node, quarter-wave per edge,
//    gathered rows scaled by normS[src].
// ---------------------------------------------------------------------------
__global__ __launch_bounds__(256) void gather_kernel(const int* __restrict__ ptr,
                                                     const int* __restrict__ indeg,
                                                     const ushort* __restrict__ sorted_src,
                                                     const float* __restrict__ normS,
                                                     const ushort* __restrict__ h,
                                                     const float* __restrict__ b,
                                                     float* __restrict__ out) {
    const int lane = threadIdx.x & 63;
    const int q = lane & 15;           // col group: cols q*4 .. q*4+3
    const int g = lane >> 4;           // edge slot 0..3
    int nid = (int)((blockIdx.x * (size_t)blockDim.x + threadIdx.x) >> 6);
    if (nid >= N_NODES) return;
    nid = __builtin_amdgcn_readfirstlane(nid);

    const int beg = ptr[nid];
    const int deg = indeg[nid];

    float a0 = 0.f, a1 = 0.f, a2 = 0.f, a3 = 0.f;
    const int nfull = deg >> 2;
    int e = beg + g;
    #pragma unroll 4
    for (int i = 0; i < nfull; ++i) {
        const int s = (int)sorted_src[e];
        e += 4;
        const float ns = normS[s];
        const uint2 v = *(const uint2*)(h + (size_t)s * OUT_F + q * 4);
        a0 = fmaf(ns, bf_lo(v.x), a0); a1 = fmaf(ns, bf_hi(v.x), a1);
        a2 = fmaf(ns, bf_lo(v.y), a2); a3 = fmaf(ns, bf_hi(v.y), a3);
    }
    const int rem = deg & 3;
    if (g < rem) {
        const int s = (int)sorted_src[beg + (deg & ~3) + g];
        const float ns = normS[s];
        const uint2 v = *(const uint2*)(h + (size_t)s * OUT_F + q * 4);
        a0 = fmaf(ns, bf_lo(v.x), a0); a1 = fmaf(ns, bf_hi(v.x), a1);
        a2 = fmaf(ns, bf_lo(v.y), a2); a3 = fmaf(ns, bf_hi(v.y), a3);
    }
    a0 += __shfl_xor(a0, 16, 64); a1 += __shfl_xor(a1, 16, 64);
    a2 += __shfl_xor(a2, 16, 64); a3 += __shfl_xor(a3, 16, 64);
    a0 += __shfl_xor(a0, 32, 64); a1 += __shfl_xor(a1, 32, 64);
    a2 += __shfl_xor(a2, 32, 64); a3 += __shfl_xor(a3, 32, 64);

    if (g == 0) {
        const float norm = rsqrtf(fmaxf((float)deg, 1.0f));
        const float4 bb = *(const float4*)(b + q * 4);
        float4 o;
        o.x = 1.0f / (1.0f + expf(-(a0 * norm + bb.x)));
        o.y = 1.0f / (1.0f + expf(-(a1 * norm + bb.y)));
        o.z = 1.0f / (1.0f + expf(-(a2 * norm + bb.z)));
        o.w = 1.0f / (1.0f + expf(-(a3 * norm + bb.w)));
        *(float4*)(out + (size_t)nid * OUT_F + q * 4) = o;
    }
}

// ---------------------------------------------------------------------------
extern "C" void kernel_launch(void* const* d_in, const int* in_sizes, int n_in,
                              void* d_out, int out_size, void* d_ws, size_t ws_size,
                              hipStream_t stream) {
    const float* feat = (const float*)d_in[0];
    const int* src    = (const int*)d_in[1];
    const int* dst    = (const int*)d_in[2];
    const float* W    = (const float*)d_in[3];
    const float* b    = (const float*)d_in[4];
    float* out = (float*)d_out;

    char* ws = (char*)d_ws;
    size_t off = 0;
    ushort* h = (ushort*)(ws + off);        off += (size_t)N_NODES * OUT_F * 2;  // 6.4 MB
    float* normS = (float*)(ws + off);      off += (size_t)N_NODES * 4;          // 200 KB
    int* indeg = (int*)(ws + off);          off += (size_t)N_NODES * 4;          // 200 KB
    int* ptr = (int*)(ws + off);            off += (size_t)N_NODES * 4;          // 200 KB
    int* bcnt = (int*)(ws + off);           off += (size_t)2 * NB * 4;           // bcntD|bcntS
    ushort* Wpk = (ushort*)(ws + off);      off += (size_t)IN_F * OUT_F * 2;     // 32 KB
    uint* pairsD = (uint*)(ws + off);       off += (size_t)NB * CAP * 4;         // 4.8 MB
    ushort* srcloc = (ushort*)(ws + off);   off += (size_t)NB * CAP * 2;         // 2.4 MB
    ushort* sorted_src = (ushort*)(ws + off); off += (size_t)NB * CAP * 2;       // 2.4 MB
    int* bcntD = bcnt;
    int* bcntS = bcnt + NB;

    prep_kernel<<<9, 256, 0, stream>>>(bcnt, W, Wpk);

    partA_kernel<<<PARTA_BLOCKS, 512, 0, stream>>>(src, dst, bcntD, bcntS, pairsD, srcloc);

    bucket_kernel<<<NB, 512, 0, stream>>>(srcloc, bcntS, normS,
                                          pairsD, bcntD, ptr, indeg, sorted_src);

    gemm_kernel<<<(N_NODES + GEMM_BM - 1) / GEMM_BM, 256, 0, stream>>>(feat, Wpk, h);

    gather_kernel<<<(N_NODES * 64 + 255) / 256, 256, 0, stream>>>(
        ptr, indeg, sorted_src, normS, h, b, out);
}

// Round 16
// 79.034 us; speedup vs baseline: 1.1914x; 1.0675x over previous
//
#include <hip/hip_runtime.h>
#include <hip/hip_bf16.h>
#include <math.h>

#define N_NODES 50000
#define N_EDGES 800000
#define IN_F 256
#define OUT_F 64

#define BKT 256            // nodes per bucket
#define NB 196             // ceil(50000/256)
#define CAP 6144           // fixed per-bucket capacity (mean 4096, sigma 64)
#define PARTA_BLOCKS 400   // 800000/400 = 2000 edges/block
#define EPB (N_EDGES / PARTA_BLOCKS)   // 2000
#define GEMM_BM 32         // 32 KB LDS -> 4 blocks/CU

typedef __attribute__((ext_vector_type(8))) short bf16x8;
typedef __attribute__((ext_vector_type(4))) float f32x4;

__device__ __forceinline__ ushort f2bf(float x) {
    __hip_bfloat16 b = __float2bfloat16(x);   // RNE
    return *reinterpret_cast<ushort*>(&b);
}
__device__ __forceinline__ float bf_lo(uint v) { return __uint_as_float(v << 16); }
__device__ __forceinline__ float bf_hi(uint v) { return __uint_as_float(v & 0xffff0000u); }

// ---------------------------------------------------------------------------
// 0) prep: block 0 zeros bcntD+bcntS; blocks 1..8 pack W into bf16 MFMA
//    B-frag layout.
// ---------------------------------------------------------------------------
__global__ __launch_bounds__(256) void prep_kernel(int* __restrict__ bcnt,
                                                   const float* __restrict__ W,
                                                   ushort* __restrict__ Wpk) {
    const int tid = threadIdx.x;
    if (blockIdx.x == 0) {
        for (int i = tid; i < 2 * NB; i += 256) bcnt[i] = 0;
    } else {
        const int gid = (blockIdx.x - 1) * 256 + tid;   // 0..2047
        const int lane = gid & 63;
        const int ct = (gid >> 6) & 3;
        const int step = gid >> 8;
        const int kg = lane >> 4;
        const int n = lane & 15;
        const float* base = W + (size_t)(step * 32 + kg * 8) * OUT_F + ct * 16 + n;
        union { ushort u[8]; uint4 v; } pk;
        #pragma unroll
        for (int j = 0; j < 8; ++j) pk.u[j] = f2bf(base[(size_t)j * OUT_F]);
        ((uint4*)Wpk)[gid] = pk.v;
    }
}

// ---------------------------------------------------------------------------
// 1) partA: dual bucket-partition, one pass, 512 threads (round-15, kept).
// ---------------------------------------------------------------------------
__global__ __launch_bounds__(512) void partA_kernel(const int* __restrict__ src,
                                                    const int* __restrict__ dst,
                                                    int* __restrict__ bcntD,
                                                    int* __restrict__ bcntS,
                                                    uint* __restrict__ pairsD,
                                                    ushort* __restrict__ srcloc) {
    __shared__ int lcntD[NB], lbaseD[NB], lcntS[NB], lbaseS[NB];
    const int tid = threadIdx.x;
    const int n4 = EPB / 4;   // 500

    for (int i = tid; i < NB; i += 512) { lcntD[i] = 0; lcntS[i] = 0; }
    __syncthreads();

    const int4* t4 = (const int4*)(dst + (size_t)blockIdx.x * EPB);
    const int4* s4 = (const int4*)(src + (size_t)blockIdx.x * EPB);

    for (int i = tid; i < n4; i += 512) {
        const int4 d = t4[i];
        const int4 s = s4[i];
        atomicAdd(&lcntD[d.x >> 8], 1); atomicAdd(&lcntS[s.x >> 8], 1);
        atomicAdd(&lcntD[d.y >> 8], 1); atomicAdd(&lcntS[s.y >> 8], 1);
        atomicAdd(&lcntD[d.z >> 8], 1); atomicAdd(&lcntS[s.z >> 8], 1);
        atomicAdd(&lcntD[d.w >> 8], 1); atomicAdd(&lcntS[s.w >> 8], 1);
    }
    __syncthreads();

    for (int i = tid; i < NB; i += 512) {
        int c = lcntD[i];
        lbaseD[i] = c ? atomicAdd(&bcntD[i], c) : 0;
        lcntD[i] = 0;
        c = lcntS[i];
        lbaseS[i] = c ? atomicAdd(&bcntS[i], c) : 0;
        lcntS[i] = 0;
    }
    __syncthreads();

    for (int i = tid; i < n4; i += 512) {
        const int4 d = t4[i];
        const int4 s = s4[i];
        int bx, off;
        #define PLACE(dd, ss)                                                  \
            bx = (dd) >> 8; off = atomicAdd(&lcntD[bx], 1);                    \
            pairsD[(size_t)bx * CAP + lbaseD[bx] + off] =                      \
                ((uint)((dd) & 255) << 16) | (uint)(ss);                       \
            bx = (ss) >> 8; off = atomicAdd(&lcntS[bx], 1);                    \
            srcloc[(size_t)bx * CAP + lbaseS[bx] + off] = (ushort)((ss) & 255);
        PLACE(d.x, s.x)
        PLACE(d.y, s.y)
        PLACE(d.z, s.z)
        PLACE(d.w, s.w)
        #undef PLACE
    }
}

// ---------------------------------------------------------------------------
// 2) bucket: fused degB + partB, 1024 threads (4 elems/thread in the
//    count/place loops, 16 waves/CU). Scan runs on waves 0-3.
// ---------------------------------------------------------------------------
__global__ __launch_bounds__(1024) void bucket_kernel(const ushort* __restrict__ srcloc,
                                                      const int* __restrict__ bcntS,
                                                      float* __restrict__ normS,
                                                      const uint* __restrict__ pairsD,
                                                      const int* __restrict__ bcntD,
                                                      int* __restrict__ ptr,
                                                      int* __restrict__ indeg,
                                                      ushort* __restrict__ sorted_src) {
    __shared__ int cnt[BKT];
    __shared__ int loff[BKT];
    __shared__ int wtot[4];
    const int bb = blockIdx.x;
    const int tid = threadIdx.x;
    const int node = bb * BKT + tid;   // valid meaning only for tid<256

    // --- phase 1: out-degree -> normS ---
    if (tid < BKT) cnt[tid] = 0;
    __syncthreads();
    const int nS = bcntS[bb];
    const ushort* sp = srcloc + (size_t)bb * CAP;
    for (int i = tid; i < nS; i += 1024) atomicAdd(&cnt[sp[i]], 1);
    __syncthreads();
    if (tid < BKT && node < N_NODES)
        normS[node] = rsqrtf(fmaxf((float)cnt[tid], 1.0f));
    __syncthreads();

    // --- phase 2: dst sort ---
    if (tid < BKT) cnt[tid] = 0;
    __syncthreads();
    const int nD = bcntD[bb];
    const uint* pb = pairsD + (size_t)bb * CAP;
    for (int i = tid; i < nD; i += 1024) atomicAdd(&cnt[pb[i] >> 16], 1);
    __syncthreads();

    // scan on waves 0-3
    if (tid < BKT) {
        const int lane = tid & 63;
        const int wave = tid >> 6;
        const int v = cnt[tid];
        int incl = v;
        #pragma unroll
        for (int d = 1; d < 64; d <<= 1) {
            int u = __shfl_up(incl, d, 64);
            if (lane >= d) incl += u;
        }
        if (lane == 63) wtot[wave] = incl;
        loff[tid] = incl - v;            // temp: intra-wave exclusive
    }
    __syncthreads();
    if (tid < BKT) {
        const int wave = tid >> 6;
        int woff = 0;
        #pragma unroll
        for (int w = 0; w < 4; ++w)
            if (w < wave) woff += wtot[w];
        const int ex = woff + loff[tid];
        loff[tid] = ex;
        const int v = cnt[tid];
        cnt[tid] = 0;                    // reuse as per-local cursor
        if (node < N_NODES) { ptr[node] = bb * CAP + ex; indeg[node] = v; }
    }
    __syncthreads();

    for (int i = tid; i < nD; i += 1024) {
        const uint p = pb[i];
        const int local = (int)(p >> 16);
        const int pos = atomicAdd(&cnt[local], 1);
        sorted_src[(size_t)bb * CAP + loff[local] + pos] = (ushort)(p & 0xFFFFu);
    }
}

// ---------------------------------------------------------------------------
// 3) gemm: h_raw = bf16(feat @ W) via MFMA, LDS-staged A, BM=32 (32 KB LDS
//    -> 4 blocks/CU). Wave w: rows (w&1)*16, cols (w>>1)*32 (2 ct-frags).
//    XOR-swizzle both sides (rule #21): linear LDS dest, pre-swizzled
//    global source chunk, same XOR on the LDS read.
// ---------------------------------------------------------------------------
__global__ __launch_bounds__(256) void gemm_kernel(const float* __restrict__ feat,
                                                   const ushort* __restrict__ Wpk,
                                                   ushort* __restrict__ h) {
    __shared__ float ftile[GEMM_BM * IN_F];   // 32 KB
    const int tid = threadIdx.x;
    const int lane = tid & 63;
    const int wave = tid >> 6;
    const int m = lane & 15;
    const int g = lane >> 4;
    const int rowBase = blockIdx.x * GEMM_BM;
    const char* fb = (const char*)feat;

    // async stage: 8 x (wave-uniform LDS base, per-lane pre-swizzled source)
    #pragma unroll
    for (int it = 0; it < 8; ++it) {
        const int R = it * 4 + wave;                        // tile row 0..31
        const int off = (lane * 16) ^ ((R & 7) << 4);       // swizzled src chunk
        int grow = rowBase + R;
        if (grow >= N_NODES) grow = N_NODES - 1;            // clamp (dup row)
        __builtin_amdgcn_global_load_lds(
            (const __attribute__((address_space(1))) void*)(fb + ((size_t)grow << 10) + off),
            (__attribute__((address_space(3))) void*)((char*)ftile + it * 4096 + wave * 1024),
            16, 0, 0);
    }
    __syncthreads();

    const int rowHalf = wave & 1;              // 0/1: rows 0-15 / 16-31
    const int colHalf = wave >> 1;             // 0/1: cols 0-31 / 32-63

    f32x4 acc[2];
    acc[0] = (f32x4){0.f, 0.f, 0.f, 0.f};
    acc[1] = (f32x4){0.f, 0.f, 0.f, 0.f};

    const int Rr = rowHalf * 16 + m;           // A-frag row within tile
    const int swz = (Rr & 7) << 4;
    const char* rowb = (const char*)ftile + (Rr << 10);
    const bf16x8* wp = (const bf16x8*)Wpk;

    #pragma unroll
    for (int step = 0; step < 8; ++step) {
        const int kb = step * 128 + g * 32;
        const float4 a0 = *(const float4*)(rowb + (kb ^ swz));
        const float4 a1 = *(const float4*)(rowb + ((kb + 16) ^ swz));
        bf16x8 aa;
        aa[0] = (short)f2bf(a0.x); aa[1] = (short)f2bf(a0.y);
        aa[2] = (short)f2bf(a0.z); aa[3] = (short)f2bf(a0.w);
        aa[4] = (short)f2bf(a1.x); aa[5] = (short)f2bf(a1.y);
        aa[6] = (short)f2bf(a1.z); aa[7] = (short)f2bf(a1.w);
        #pragma unroll
        for (int ct = 0; ct < 2; ++ct)
            acc[ct] = __builtin_amdgcn_mfma_f32_16x16x32_bf16(
                aa, wp[(step * 4 + colHalf * 2 + ct) * 64 + lane], acc[ct], 0, 0, 0);
    }

    // C-frag: col = colHalf*32 + ct*16 + m, row = rowBase + rowHalf*16 + g*4 + j
    #pragma unroll
    for (int j = 0; j < 4; ++j) {
        const int row = rowBase + rowHalf * 16 + g * 4 + j;
        if (row < N_NODES) {
            #pragma unroll
            for (int ct = 0; ct < 2; ++ct)
                h[(size_t)row * OUT_F + colHalf * 32 + ct * 16 + m] = f2bf(acc[ct][j]);
        }
    }
}

// ---------------------------------------------------------------------------
// 4) Gather + epilogue: one wave per dst node, quarter-wave per edge,
//    gathered rows scaled by normS[src].
// ---------------------------------------------------------------------------
__global__ __launch_bounds__(256) void gather_kernel(const int* __restrict__ ptr,
                                                     const int* __restrict__ indeg,
                                                     const ushort* __restrict__ sorted_src,
                                                     const float* __restrict__ normS,
                                                     const ushort* __restrict__ h,
                                                     const float* __restrict__ b,
                                                     float* __restrict__ out) {
    const int lane = threadIdx.x & 63;
    const int q = lane & 15;           // col group: cols q*4 .. q*4+3
    const int g = lane >> 4;           // edge slot 0..3
    int nid = (int)((blockIdx.x * (size_t)blockDim.x + threadIdx.x) >> 6);
    if (nid >= N_NODES) return;
    nid = __builtin_amdgcn_readfirstlane(nid);

    const int beg = ptr[nid];
    const int deg = indeg[nid];

    float a0 = 0.f, a1 = 0.f, a2 = 0.f, a3 = 0.f;
    const int nfull = deg >> 2;
    int e = beg + g;
    #pragma unroll 4
    for (int i = 0; i < nfull; ++i) {
        const int s = (int)sorted_src[e];
        e += 4;
        const float ns = normS[s];
        const uint2 v = *(const uint2*)(h + (size_t)s * OUT_F + q * 4);
        a0 = fmaf(ns, bf_lo(v.x), a0); a1 = fmaf(ns, bf_hi(v.x), a1);
        a2 = fmaf(ns, bf_lo(v.y), a2); a3 = fmaf(ns, bf_hi(v.y), a3);
    }
    const int rem = deg & 3;
    if (g < rem) {
        const int s = (int)sorted_src[beg + (deg & ~3) + g];
        const float ns = normS[s];
        const uint2 v = *(const uint2*)(h + (size_t)s * OUT_F + q * 4);
        a0 = fmaf(ns, bf_lo(v.x), a0); a1 = fmaf(ns, bf_hi(v.x), a1);
        a2 = fmaf(ns, bf_lo(v.y), a2); a3 = fmaf(ns, bf_hi(v.y), a3);
    }
    a0 += __shfl_xor(a0, 16, 64); a1 += __shfl_xor(a1, 16, 64);
    a2 += __shfl_xor(a2, 16, 64); a3 += __shfl_xor(a3, 16, 64);
    a0 += __shfl_xor(a0, 32, 64); a1 += __shfl_xor(a1, 32, 64);
    a2 += __shfl_xor(a2, 32, 64); a3 += __shfl_xor(a3, 32, 64);

    if (g == 0) {
        const float norm = rsqrtf(fmaxf((float)deg, 1.0f));
        const float4 bb = *(const float4*)(b + q * 4);
        float4 o;
        o.x = 1.0f / (1.0f + expf(-(a0 * norm + bb.x)));
        o.y = 1.0f / (1.0f + expf(-(a1 * norm + bb.y)));
        o.z = 1.0f / (1.0f + expf(-(a2 * norm + bb.z)));
        o.w = 1.0f / (1.0f + expf(-(a3 * norm + bb.w)));
        *(float4*)(out + (size_t)nid * OUT_F + q * 4) = o;
    }
}

// ---------------------------------------------------------------------------
extern "C" void kernel_launch(void* const* d_in, const int* in_sizes, int n_in,
                              void* d_out, int out_size, void* d_ws, size_t ws_size,
                              hipStream_t stream) {
    const float* feat = (const float*)d_in[0];
    const int* src    = (const int*)d_in[1];
    const int* dst    = (const int*)d_in[2];
    const float* W    = (const float*)d_in[3];
    const float* b    = (const float*)d_in[4];
    float* out = (float*)d_out;

    char* ws = (char*)d_ws;
    size_t off = 0;
    ushort* h = (ushort*)(ws + off);        off += (size_t)N_NODES * OUT_F * 2;  // 6.4 MB
    float* normS = (float*)(ws + off);      off += (size_t)N_NODES * 4;          // 200 KB
    int* indeg = (int*)(ws + off);          off += (size_t)N_NODES * 4;          // 200 KB
    int* ptr = (int*)(ws + off);            off += (size_t)N_NODES * 4;          // 200 KB
    int* bcnt = (int*)(ws + off);           off += (size_t)2 * NB * 4;           // bcntD|bcntS
    ushort* Wpk = (ushort*)(ws + off);      off += (size_t)IN_F * OUT_F * 2;     // 32 KB
    uint* pairsD = (uint*)(ws + off);       off += (size_t)NB * CAP * 4;         // 4.8 MB
    ushort* srcloc = (ushort*)(ws + off);   off += (size_t)NB * CAP * 2;         // 2.4 MB
    ushort* sorted_src = (ushort*)(ws + off); off += (size_t)NB * CAP * 2;       // 2.4 MB
    int* bcntD = bcnt;
    int* bcntS = bcnt + NB;

    prep_kernel<<<9, 256, 0, stream>>>(bcnt, W, Wpk);

    partA_kernel<<<PARTA_BLOCKS, 512, 0, stream>>>(src, dst, bcntD, bcntS, pairsD, srcloc);

    bucket_kernel<<<NB, 1024, 0, stream>>>(srcloc, bcntS, normS,
                                           pairsD, bcntD, ptr, indeg, sorted_src);

    gemm_kernel<<<(N_NODES + GEMM_BM - 1) / GEMM_BM, 256, 0, stream>>>(feat, Wpk, h);

    gather_kernel<<<(N_NODES * 64 + 255) / 256, 256, 0, stream>>>(
        ptr, indeg, sorted_src, normS, h, b, out);
}

// Round 17
// 75.395 us; speedup vs baseline: 1.2489x; 1.0483x over previous
//
#include <hip/hip_runtime.h>
#include <hip/hip_bf16.h>
#include <math.h>

#define N_NODES 50000
#define N_EDGES 800000
#define IN_F 256
#define OUT_F 64

#define BKT 256            // nodes per bucket
#define NB 196             // ceil(50000/256)
#define CAP 6144           // fixed per-bucket capacity (mean 4096, sigma 64)
#define PARTA_BLOCKS 400   // 800000/400 = 2000 edges/block
#define EPB (N_EDGES / PARTA_BLOCKS)   // 2000
#define GEMM_BM 32         // 32 KB LDS -> 4 blocks/CU

typedef __attribute__((ext_vector_type(8))) short bf16x8;
typedef __attribute__((ext_vector_type(4))) float f32x4;

__device__ __forceinline__ ushort f2bf(float x) {
    __hip_bfloat16 b = __float2bfloat16(x);   // RNE
    return *reinterpret_cast<ushort*>(&b);
}
__device__ __forceinline__ float bf_lo(uint v) { return __uint_as_float(v << 16); }
__device__ __forceinline__ float bf_hi(uint v) { return __uint_as_float(v & 0xffff0000u); }

// ---------------------------------------------------------------------------
// 0) prep: block 0 zeros bcntD+bcntS; blocks 1..8 pack W into bf16 MFMA
//    B-frag layout.
// ---------------------------------------------------------------------------
__global__ __launch_bounds__(256) void prep_kernel(int* __restrict__ bcnt,
                                                   const float* __restrict__ W,
                                                   ushort* __restrict__ Wpk) {
    const int tid = threadIdx.x;
    if (blockIdx.x == 0) {
        for (int i = tid; i < 2 * NB; i += 256) bcnt[i] = 0;
    } else {
        const int gid = (blockIdx.x - 1) * 256 + tid;   // 0..2047
        const int lane = gid & 63;
        const int ct = (gid >> 6) & 3;
        const int step = gid >> 8;
        const int kg = lane >> 4;
        const int n = lane & 15;
        const float* base = W + (size_t)(step * 32 + kg * 8) * OUT_F + ct * 16 + n;
        union { ushort u[8]; uint4 v; } pk;
        #pragma unroll
        for (int j = 0; j < 8; ++j) pk.u[j] = f2bf(base[(size_t)j * OUT_F]);
        ((uint4*)Wpk)[gid] = pk.v;
    }
}

// ---------------------------------------------------------------------------
// 1) partA: dual bucket-partition with LDS-staged WRITE COMBINING.
//    Entries are sorted into LDS staging by bucket, then written out in
//    staging order: consecutive lanes -> consecutive addresses within each
//    bucket run (~10 entries) -> ~6-8 line transactions per wave store
//    instead of ~60 (the round-16 scatter cost ~25 us on this).
// ---------------------------------------------------------------------------
__global__ __launch_bounds__(512) void partA_kernel(const int* __restrict__ src,
                                                    const int* __restrict__ dst,
                                                    int* __restrict__ bcntD,
                                                    int* __restrict__ bcntS,
                                                    uint* __restrict__ pairsD,
                                                    ushort* __restrict__ srcloc) {
    __shared__ int2 ed[EPB];              // 16 KB  (dst, src)
    __shared__ uint stgD[EPB];            // 8 KB   staged pairs, bucket-sorted
    __shared__ ushort bktD[EPB];          // 4 KB   bucket id per staged slot
    __shared__ ushort stgS[EPB];          // 4 KB   staged src-locals
    __shared__ ushort bktS[EPB];          // 4 KB
    __shared__ int lcntD[256], lcntS[256];    // counts -> cursors
    __shared__ int ldofD[256], ldofS[256];    // local exclusive offsets
    __shared__ int lbaseD[NB], lbaseS[NB];    // global base offsets (in-bucket)
    __shared__ int wtotD[4], wtotS[4];
    const int tid = threadIdx.x;
    const int n4 = EPB / 4;   // 500

    for (int i = tid; i < 256; i += 512) { lcntD[i] = 0; lcntS[i] = 0; }
    __syncthreads();

    // load slice to LDS + count buckets
    const int4* t4 = (const int4*)(dst + (size_t)blockIdx.x * EPB);
    const int4* s4 = (const int4*)(src + (size_t)blockIdx.x * EPB);
    for (int i = tid; i < n4; i += 512) {
        const int4 d = t4[i];
        const int4 s = s4[i];
        ed[4 * i + 0] = (int2){d.x, s.x};
        ed[4 * i + 1] = (int2){d.y, s.y};
        ed[4 * i + 2] = (int2){d.z, s.z};
        ed[4 * i + 3] = (int2){d.w, s.w};
        atomicAdd(&lcntD[d.x >> 8], 1); atomicAdd(&lcntS[s.x >> 8], 1);
        atomicAdd(&lcntD[d.y >> 8], 1); atomicAdd(&lcntS[s.y >> 8], 1);
        atomicAdd(&lcntD[d.z >> 8], 1); atomicAdd(&lcntS[s.z >> 8], 1);
        atomicAdd(&lcntD[d.w >> 8], 1); atomicAdd(&lcntS[s.w >> 8], 1);
    }
    __syncthreads();

    // reserve global bucket regions
    for (int i = tid; i < NB; i += 512) {
        const int cD = lcntD[i];
        lbaseD[i] = cD ? atomicAdd(&bcntD[i], cD) : 0;
        const int cS = lcntS[i];
        lbaseS[i] = cS ? atomicAdd(&bcntS[i], cS) : 0;
    }

    // block exclusive scan of both count arrays (waves 0-3)
    if (tid < 256) {
        const int lane = tid & 63;
        const int wave = tid >> 6;
        const int vD = lcntD[tid], vS = lcntS[tid];
        int iD = vD, iS = vS;
        #pragma unroll
        for (int d = 1; d < 64; d <<= 1) {
            const int uD = __shfl_up(iD, d, 64);
            const int uS = __shfl_up(iS, d, 64);
            if (lane >= d) { iD += uD; iS += uS; }
        }
        if (lane == 63) { wtotD[wave] = iD; wtotS[wave] = iS; }
        ldofD[tid] = iD - vD;
        ldofS[tid] = iS - vS;
    }
    __syncthreads();
    if (tid < 256) {
        const int wave = tid >> 6;
        int woD = 0, woS = 0;
        #pragma unroll
        for (int w = 0; w < 4; ++w)
            if (w < wave) { woD += wtotD[w]; woS += wtotS[w]; }
        ldofD[tid] += woD;
        ldofS[tid] += woS;
        lcntD[tid] = 0;      // reuse as cursors
        lcntS[tid] = 0;
    }
    __syncthreads();

    // place into LDS staging, sorted by bucket
    for (int i = tid; i < EPB; i += 512) {
        const int2 e = ed[i];
        int bx = e.x >> 8;
        int pos = atomicAdd(&lcntD[bx], 1);
        int sl = ldofD[bx] + pos;
        stgD[sl] = ((uint)(e.x & 255) << 16) | (uint)e.y;
        bktD[sl] = (ushort)bx;
        bx = e.y >> 8;
        pos = atomicAdd(&lcntS[bx], 1);
        sl = ldofS[bx] + pos;
        stgS[sl] = (ushort)(e.y & 255);
        bktS[sl] = (ushort)bx;
    }
    __syncthreads();

    // write out in staging order: consecutive lanes -> consecutive dests
    for (int i = tid; i < EPB; i += 512) {
        int b = bktD[i];
        pairsD[(size_t)b * CAP + lbaseD[b] + (i - ldofD[b])] = stgD[i];
        b = bktS[i];
        srcloc[(size_t)b * CAP + lbaseS[b] + (i - ldofS[b])] = stgS[i];
    }
}

// ---------------------------------------------------------------------------
// 2) bucket: fused degB + partB, 1024 threads (round-16, kept).
// ---------------------------------------------------------------------------
__global__ __launch_bounds__(1024) void bucket_kernel(const ushort* __restrict__ srcloc,
                                                      const int* __restrict__ bcntS,
                                                      float* __restrict__ normS,
                                                      const uint* __restrict__ pairsD,
                                                      const int* __restrict__ bcntD,
                                                      int* __restrict__ ptr,
                                                      int* __restrict__ indeg,
                                                      ushort* __restrict__ sorted_src) {
    __shared__ int cnt[BKT];
    __shared__ int loff[BKT];
    __shared__ int wtot[4];
    const int bb = blockIdx.x;
    const int tid = threadIdx.x;
    const int node = bb * BKT + tid;   // valid meaning only for tid<256

    // --- phase 1: out-degree -> normS ---
    if (tid < BKT) cnt[tid] = 0;
    __syncthreads();
    const int nS = bcntS[bb];
    const ushort* sp = srcloc + (size_t)bb * CAP;
    for (int i = tid; i < nS; i += 1024) atomicAdd(&cnt[sp[i]], 1);
    __syncthreads();
    if (tid < BKT && node < N_NODES)
        normS[node] = rsqrtf(fmaxf((float)cnt[tid], 1.0f));
    __syncthreads();

    // --- phase 2: dst sort ---
    if (tid < BKT) cnt[tid] = 0;
    __syncthreads();
    const int nD = bcntD[bb];
    const uint* pb = pairsD + (size_t)bb * CAP;
    for (int i = tid; i < nD; i += 1024) atomicAdd(&cnt[pb[i] >> 16], 1);
    __syncthreads();

    // scan on waves 0-3
    if (tid < BKT) {
        const int lane = tid & 63;
        const int wave = tid >> 6;
        const int v = cnt[tid];
        int incl = v;
        #pragma unroll
        for (int d = 1; d < 64; d <<= 1) {
            int u = __shfl_up(incl, d, 64);
            if (lane >= d) incl += u;
        }
        if (lane == 63) wtot[wave] = incl;
        loff[tid] = incl - v;            // temp: intra-wave exclusive
    }
    __syncthreads();
    if (tid < BKT) {
        const int wave = tid >> 6;
        int woff = 0;
        #pragma unroll
        for (int w = 0; w < 4; ++w)
            if (w < wave) woff += wtot[w];
        const int ex = woff + loff[tid];
        loff[tid] = ex;
        const int v = cnt[tid];
        cnt[tid] = 0;                    // reuse as per-local cursor
        if (node < N_NODES) { ptr[node] = bb * CAP + ex; indeg[node] = v; }
    }
    __syncthreads();

    for (int i = tid; i < nD; i += 1024) {
        const uint p = pb[i];
        const int local = (int)(p >> 16);
        const int pos = atomicAdd(&cnt[local], 1);
        sorted_src[(size_t)bb * CAP + loff[local] + pos] = (ushort)(p & 0xFFFFu);
    }
}

// ---------------------------------------------------------------------------
// 3) gemm: h_raw = bf16(feat @ W) via MFMA, LDS-staged A, BM=32 (round-16).
// ---------------------------------------------------------------------------
__global__ __launch_bounds__(256) void gemm_kernel(const float* __restrict__ feat,
                                                   const ushort* __restrict__ Wpk,
                                                   ushort* __restrict__ h) {
    __shared__ float ftile[GEMM_BM * IN_F];   // 32 KB
    const int tid = threadIdx.x;
    const int lane = tid & 63;
    const int wave = tid >> 6;
    const int m = lane & 15;
    const int g = lane >> 4;
    const int rowBase = blockIdx.x * GEMM_BM;
    const char* fb = (const char*)feat;

    #pragma unroll
    for (int it = 0; it < 8; ++it) {
        const int R = it * 4 + wave;                        // tile row 0..31
        const int off = (lane * 16) ^ ((R & 7) << 4);       // swizzled src chunk
        int grow = rowBase + R;
        if (grow >= N_NODES) grow = N_NODES - 1;            // clamp (dup row)
        __builtin_amdgcn_global_load_lds(
            (const __attribute__((address_space(1))) void*)(fb + ((size_t)grow << 10) + off),
            (__attribute__((address_space(3))) void*)((char*)ftile + it * 4096 + wave * 1024),
            16, 0, 0);
    }
    __syncthreads();

    const int rowHalf = wave & 1;              // 0/1: rows 0-15 / 16-31
    const int colHalf = wave >> 1;             // 0/1: cols 0-31 / 32-63

    f32x4 acc[2];
    acc[0] = (f32x4){0.f, 0.f, 0.f, 0.f};
    acc[1] = (f32x4){0.f, 0.f, 0.f, 0.f};

    const int Rr = rowHalf * 16 + m;           // A-frag row within tile
    const int swz = (Rr & 7) << 4;
    const char* rowb = (const char*)ftile + (Rr << 10);
    const bf16x8* wp = (const bf16x8*)Wpk;

    #pragma unroll
    for (int step = 0; step < 8; ++step) {
        const int kb = step * 128 + g * 32;
        const float4 a0 = *(const float4*)(rowb + (kb ^ swz));
        const float4 a1 = *(const float4*)(rowb + ((kb + 16) ^ swz));
        bf16x8 aa;
        aa[0] = (short)f2bf(a0.x); aa[1] = (short)f2bf(a0.y);
        aa[2] = (short)f2bf(a0.z); aa[3] = (short)f2bf(a0.w);
        aa[4] = (short)f2bf(a1.x); aa[5] = (short)f2bf(a1.y);
        aa[6] = (short)f2bf(a1.z); aa[7] = (short)f2bf(a1.w);
        #pragma unroll
        for (int ct = 0; ct < 2; ++ct)
            acc[ct] = __builtin_amdgcn_mfma_f32_16x16x32_bf16(
                aa, wp[(step * 4 + colHalf * 2 + ct) * 64 + lane], acc[ct], 0, 0, 0);
    }

    // C-frag: col = colHalf*32 + ct*16 + m, row = rowBase + rowHalf*16 + g*4 + j
    #pragma unroll
    for (int j = 0; j < 4; ++j) {
        const int row = rowBase + rowHalf * 16 + g * 4 + j;
        if (row < N_NODES) {
            #pragma unroll
            for (int ct = 0; ct < 2; ++ct)
                h[(size_t)row * OUT_F + colHalf * 32 + ct * 16 + m] = f2bf(acc[ct][j]);
        }
    }
}

// ---------------------------------------------------------------------------
// 4) Gather + epilogue: one wave per dst node, quarter-wave per edge,
//    gathered rows scaled by normS[src].
// ---------------------------------------------------------------------------
__global__ __launch_bounds__(256) void gather_kernel(const int* __restrict__ ptr,
                                                     const int* __restrict__ indeg,
                                                     const ushort* __restrict__ sorted_src,
                                                     const float* __restrict__ normS,
                                                     const ushort* __restrict__ h,
                                                     const float* __restrict__ b,
                                                     float* __restrict__ out) {
    const int lane = threadIdx.x & 63;
    const int q = lane & 15;           // col group: cols q*4 .. q*4+3
    const int g = lane >> 4;           // edge slot 0..3
    int nid = (int)((blockIdx.x * (size_t)blockDim.x + threadIdx.x) >> 6);
    if (nid >= N_NODES) return;
    nid = __builtin_amdgcn_readfirstlane(nid);

    const int beg = ptr[nid];
    const int deg = indeg[nid];

    float a0 = 0.f, a1 = 0.f, a2 = 0.f, a3 = 0.f;
    const int nfull = deg >> 2;
    int e = beg + g;
    #pragma unroll 4
    for (int i = 0; i < nfull; ++i) {
        const int s = (int)sorted_src[e];
        e += 4;
        const float ns = normS[s];
        const uint2 v = *(const uint2*)(h + (size_t)s * OUT_F + q * 4);
        a0 = fmaf(ns, bf_lo(v.x), a0); a1 = fmaf(ns, bf_hi(v.x), a1);
        a2 = fmaf(ns, bf_lo(v.y), a2); a3 = fmaf(ns, bf_hi(v.y), a3);
    }
    const int rem = deg & 3;
    if (g < rem) {
        const int s = (int)sorted_src[beg + (deg & ~3) + g];
        const float ns = normS[s];
        const uint2 v = *(const uint2*)(h + (size_t)s * OUT_F + q * 4);
        a0 = fmaf(ns, bf_lo(v.x), a0); a1 = fmaf(ns, bf_hi(v.x), a1);
        a2 = fmaf(ns, bf_lo(v.y), a2); a3 = fmaf(ns, bf_hi(v.y), a3);
    }
    a0 += __shfl_xor(a0, 16, 64); a1 += __shfl_xor(a1, 16, 64);
    a2 += __shfl_xor(a2, 16, 64); a3 += __shfl_xor(a3, 16, 64);
    a0 += __shfl_xor(a0, 32, 64); a1 += __shfl_xor(a1, 32, 64);
    a2 += __shfl_xor(a2, 32, 64); a3 += __shfl_xor(a3, 32, 64);

    if (g == 0) {
        const float norm = rsqrtf(fmaxf((float)deg, 1.0f));
        const float4 bb = *(const float4*)(b + q * 4);
        float4 o;
        o.x = 1.0f / (1.0f + expf(-(a0 * norm + bb.x)));
        o.y = 1.0f / (1.0f + expf(-(a1 * norm + bb.y)));
        o.z = 1.0f / (1.0f + expf(-(a2 * norm + bb.z)));
        o.w = 1.0f / (1.0f + expf(-(a3 * norm + bb.w)));
        *(float4*)(out + (size_t)nid * OUT_F + q * 4) = o;
    }
}

// ---------------------------------------------------------------------------
extern "C" void kernel_launch(void* const* d_in, const int* in_sizes, int n_in,
                              void* d_out, int out_size, void* d_ws, size_t ws_size,
                              hipStream_t stream) {
    const float* feat = (const float*)d_in[0];
    const int* src    = (const int*)d_in[1];
    const int* dst    = (const int*)d_in[2];
    const float* W    = (const float*)d_in[3];
    const float* b    = (const float*)d_in[4];
    float* out = (float*)d_out;

    char* ws = (char*)d_ws;
    size_t off = 0;
    ushort* h = (ushort*)(ws + off);        off += (size_t)N_NODES * OUT_F * 2;  // 6.4 MB
    float* normS = (float*)(ws + off);      off += (size_t)N_NODES * 4;          // 200 KB
    int* indeg = (int*)(ws + off);          off += (size_t)N_NODES * 4;          // 200 KB
    int* ptr = (int*)(ws + off);            off += (size_t)N_NODES * 4;          // 200 KB
    int* bcnt = (int*)(ws + off);           off += (size_t)2 * NB * 4;           // bcntD|bcntS
    ushort* Wpk = (ushort*)(ws + off);      off += (size_t)IN_F * OUT_F * 2;     // 32 KB
    uint* pairsD = (uint*)(ws + off);       off += (size_t)NB * CAP * 4;         // 4.8 MB
    ushort* srcloc = (ushort*)(ws + off);   off += (size_t)NB * CAP * 2;         // 2.4 MB
    ushort* sorted_src = (ushort*)(ws + off); off += (size_t)NB * CAP * 2;       // 2.4 MB
    int* bcntD = bcnt;
    int* bcntS = bcnt + NB;

    prep_kernel<<<9, 256, 0, stream>>>(bcnt, W, Wpk);

    partA_kernel<<<PARTA_BLOCKS, 512, 0, stream>>>(src, dst, bcntD, bcntS, pairsD, srcloc);

    bucket_kernel<<<NB, 1024, 0, stream>>>(srcloc, bcntS, normS,
                                           pairsD, bcntD, ptr, indeg, sorted_src);

    gemm_kernel<<<(N_NODES + GEMM_BM - 1) / GEMM_BM, 256, 0, stream>>>(feat, Wpk, h);

    gather_kernel<<<(N_NODES * 64 + 255) / 256, 256, 0, stream>>>(
        ptr, indeg, sorted_src, normS, h, b, out);
}